// Round 11
// baseline (176.757 us; speedup 1.0000x reference)
//
#include <hip/hip_runtime.h>
#include <hip/hip_bf16.h>

#define NUM_RATINGS 10
#define GW 4096   // persistent waves = 256 blocks x 16 waves (1024 threads)

typedef short bf16x8 __attribute__((ext_vector_type(8)));
typedef float f32x4 __attribute__((ext_vector_type(4)));

// ---- RNE f32 -> bf16 packing (static indexing only) ----
static __device__ __forceinline__ bf16x8 rne8(float4 a, float4 b) {
    float f[8] = {a.x, a.y, a.z, a.w, b.x, b.y, b.z, b.w};
    union { unsigned short us[8]; bf16x8 v; } U;
    #pragma unroll
    for (int i = 0; i < 8; ++i) {
        unsigned u = __float_as_uint(f[i]);
        U.us[i] = (unsigned short)((u + 0x7fffu + ((u >> 16) & 1u)) >> 16);
    }
    return U.v;
}

static __device__ __forceinline__ bf16x8 rne8s(float4 a, float4 b, float s) {
    float f[8] = {a.x, a.y, a.z, a.w, b.x, b.y, b.z, b.w};
    union { unsigned short us[8]; bf16x8 v; } U;
    #pragma unroll
    for (int i = 0; i < 8; ++i) {
        unsigned u = __float_as_uint(f[i] * s);
        U.us[i] = (unsigned short)((u + 0x7fffu + ((u >> 16) & 1u)) >> 16);
    }
    return U.v;
}

// ---------------- W -> bf16 B-fragment precompute (verified round 6) -------
// wf[(r*8 + j)*64 + lane], j = tt*2 + ks.
// Lane l (eh=l&15, kg=l>>4) holds W[r][16*tt + eh][32*ks + 8*kg + i], i=0..7.
__global__ void k_wfrag(const float* __restrict__ w, bf16x8* __restrict__ wf) {
    int r = blockIdx.x;
    int lane = threadIdx.x & 63;
    int eh = lane & 15, kg = lane >> 4;
    #pragma unroll
    for (int j = 0; j < 8; ++j) {
        int tt = j >> 1, ks = j & 1;
        const float4* p = reinterpret_cast<const float4*>(
            w + ((size_t)r << 12) + (size_t)(16 * tt + eh) * 64 + 32 * ks + 8 * kg);
        wf[(r * 8 + j) * 64 + lane] = rne8(p[0], p[1]);
    }
}

// meta generation S for chunk CC: per-lane edges (eh, eh+16) of the chunk
#define MLOAD(S, CC) { \
    int cc_ = (CC); if (cc_ > NCm1) cc_ = NCm1; \
    int b_ = cc_ * 32 + eh; \
    int ea_ = b_ > Em1 ? Em1 : b_; \
    int eb_ = (b_ + 16) > Em1 ? Em1 : (b_ + 16); \
    nd##S##0 = enode[ea_]; rt##S##0 = erating[ea_]; sc##S##0 = invc[ea_]; \
    nd##S##1 = enode[eb_]; rt##S##1 = erating[eb_]; sc##S##1 = invc[eb_]; }

// x set XS for the chunk whose meta is in MS
#define XLOADM(XS, MS) { \
    const float4* pa_ = reinterpret_cast<const float4*>(embed + ((size_t)nd##MS##0 << 6)); \
    const float4* pb_ = reinterpret_cast<const float4*>(embed + ((size_t)nd##MS##1 << 6)); \
    x##XS##00 = pa_[2 * kg]; x##XS##01 = pa_[2 * kg + 1]; \
    x##XS##02 = pa_[8 + 2 * kg]; x##XS##03 = pa_[9 + 2 * kg]; \
    x##XS##10 = pb_[2 * kg]; x##XS##11 = pb_[2 * kg + 1]; \
    x##XS##12 = pb_[8 + 2 * kg]; x##XS##13 = pb_[9 + 2 * kg]; }

// process chunk c (meta MP, x XC); prefetch x(c+GW) from MQ and meta(c+2GW) into MP
#define ITER(MP, MQ, XC, XN) { \
    XLOADM(XN, MQ) \
    int snd0 = nd##MP##0, snd1 = nd##MP##1; \
    int srt0 = rt##MP##0, srt1 = rt##MP##1; \
    float ssc0 = sc##MP##0, ssc1 = sc##MP##1; \
    bf16x8 a00 = rne8s(x##XC##00, x##XC##01, ssc0); \
    bf16x8 a01 = rne8s(x##XC##02, x##XC##03, ssc0); \
    bf16x8 a10 = rne8s(x##XC##10, x##XC##11, ssc1); \
    bf16x8 a11 = rne8s(x##XC##12, x##XC##13, ssc1); \
    MLOAD(MP, c + 2 * GW) \
    unsigned pres0 = 0, pres1 = 0; \
    _Pragma("unroll") \
    for (int rq = 0; rq < NUM_RATINGS; ++rq) { \
        if (__any(srt0 == rq)) pres0 |= 1u << rq; \
        if (__any(srt1 == rq)) pres1 |= 1u << rq; \
    } \
    f32x4 ac0[4], ac1[4]; \
    _Pragma("unroll") \
    for (int t_ = 0; t_ < 4; ++t_) { \
        ac0[t_] = (f32x4){0.f, 0.f, 0.f, 0.f}; \
        ac1[t_] = (f32x4){0.f, 0.f, 0.f, 0.f}; \
    } \
    _Pragma("unroll 1") \
    for (int r_ = 0; r_ < NUM_RATINGS; ++r_) { \
        if (!(((pres0 | pres1) >> r_) & 1u)) continue; \
        bf16x8 Bv[8]; \
        _Pragma("unroll") \
        for (int j_ = 0; j_ < 8; ++j_) Bv[j_] = swf[(r_ * 8 + j_) * 64 + lane]; \
        bf16x8 z_ = (bf16x8)(short)0; \
        if ((pres0 >> r_) & 1u) { \
            bf16x8 m0_ = (srt0 == r_) ? a00 : z_; \
            bf16x8 m1_ = (srt0 == r_) ? a01 : z_; \
            _Pragma("unroll") \
            for (int t_ = 0; t_ < 4; ++t_) { \
                ac0[t_] = __builtin_amdgcn_mfma_f32_16x16x32_bf16(m0_, Bv[2 * t_],     ac0[t_], 0, 0, 0); \
                ac0[t_] = __builtin_amdgcn_mfma_f32_16x16x32_bf16(m1_, Bv[2 * t_ + 1], ac0[t_], 0, 0, 0); \
            } \
        } \
        if ((pres1 >> r_) & 1u) { \
            bf16x8 m0_ = (srt1 == r_) ? a10 : z_; \
            bf16x8 m1_ = (srt1 == r_) ? a11 : z_; \
            _Pragma("unroll") \
            for (int t_ = 0; t_ < 4; ++t_) { \
                ac1[t_] = __builtin_amdgcn_mfma_f32_16x16x32_bf16(m0_, Bv[2 * t_],     ac1[t_], 0, 0, 0); \
                ac1[t_] = __builtin_amdgcn_mfma_f32_16x16x32_bf16(m1_, Bv[2 * t_ + 1], ac1[t_], 0, 0, 0); \
            } \
        } \
    } \
    int kg4 = kg << 2; \
    _Pragma("unroll") \
    for (int rg = 0; rg < 4; ++rg) { \
        int er0 = c * 32 + kg4 + rg; \
        int nda = __shfl(snd0, kg4 + rg, 64); \
        if (er0 < E) { \
            float* po = out + ((size_t)nda << 6) + eh; \
            __builtin_nontemporal_store(ac0[0][rg], po); \
            __builtin_nontemporal_store(ac0[1][rg], po + 16); \
            __builtin_nontemporal_store(ac0[2][rg], po + 32); \
            __builtin_nontemporal_store(ac0[3][rg], po + 48); \
        } \
        int er1 = c * 32 + 16 + kg4 + rg; \
        int ndb = __shfl(snd1, kg4 + rg, 64); \
        if (er1 < E) { \
            float* po = out + ((size_t)ndb << 6) + eh; \
            __builtin_nontemporal_store(ac1[0][rg], po); \
            __builtin_nontemporal_store(ac1[1][rg], po + 16); \
            __builtin_nontemporal_store(ac1[2][rg], po + 32); \
            __builtin_nontemporal_store(ac1[3][rg], po + 48); \
        } \
    } \
}

// ---------------- persistent main ----------------
// Natural edge order (coalesced IO), masked MFMA over present ratings,
// all-ratings B cached in 80 KiB LDS, 2-deep cross-chunk pipeline.
// 1024-thread blocks: ONE block per CU (16 waves = 4 waves/SIMD) sharing a
// single 80 KiB LDS copy. VGPR cap at 16 waves/CU is 128 >= our ~90 need —
// avoids round-10's launch_bounds-induced 64-VGPR spill cliff.
// D layout (m89, verified r4-r9): row(edge) = 4*kg + rg, col(out) = 16*tt + eh.
__global__ __launch_bounds__(1024, 1) void k_main(
    const float* __restrict__ embed, const bf16x8* __restrict__ wf,
    const float* __restrict__ invc, const int* __restrict__ enode,
    const int* __restrict__ erating, float* __restrict__ out, int E) {

    __shared__ bf16x8 swf[NUM_RATINGS * 8 * 64];   // 80 KiB
    for (int i = threadIdx.x; i < NUM_RATINGS * 8 * 64; i += 1024)
        swf[i] = wf[i];
    __syncthreads();

    int lane = threadIdx.x & 63;
    int wv = threadIdx.x >> 6;          // 0..15
    int eh = lane & 15, kg = lane >> 4;

    int NC = (E + 31) >> 5;
    int NCm1 = NC - 1, Em1 = E - 1;
    int c = blockIdx.x * 16 + wv;
    if (c >= NC) return;

    int ndP0, ndP1, rtP0, rtP1; float scP0, scP1;
    int ndQ0, ndQ1, rtQ0, rtQ1; float scQ0, scQ1;
    float4 xX00, xX01, xX02, xX03, xX10, xX11, xX12, xX13;
    float4 xY00, xY01, xY02, xY03, xY10, xY11, xY12, xY13;

    MLOAD(P, c)
    MLOAD(Q, c + GW)
    XLOADM(X, P)

    while (1) {
        ITER(P, Q, X, Y)
        c += GW; if (c >= NC) break;
        ITER(Q, P, Y, X)
        c += GW; if (c >= NC) break;
    }
}

extern "C" void kernel_launch(void* const* d_in, const int* in_sizes, int n_in,
                              void* d_out, int out_size, void* d_ws, size_t ws_size,
                              hipStream_t stream) {
    const float* embed   = (const float*)d_in[0];
    const float* weights = (const float*)d_in[1];
    const float* invc    = (const float*)d_in[2];
    const int*   enode   = (const int*)d_in[3];
    const int*   erating = (const int*)d_in[4];
    float* out = (float*)d_out;

    int E = in_sizes[3];

    bf16x8* wf = (bf16x8*)d_ws;   // 80 KiB W fragments

    hipLaunchKernelGGL(k_wfrag, dim3(NUM_RATINGS), dim3(64), 0, stream, weights, wf);
    hipLaunchKernelGGL(k_main, dim3(GW / 16), dim3(1024), 0, stream,
                       embed, wf, invc, enode, erating, out, E);
}

// Round 12
// 176.084 us; speedup vs baseline: 1.0038x; 1.0038x over previous
//
#include <hip/hip_runtime.h>
#include <hip/hip_bf16.h>

#define NUM_RATINGS 10
#define GW 4096   // persistent waves = 256 blocks x 16 waves (1024 threads)

typedef short bf16x8 __attribute__((ext_vector_type(8)));
typedef float f32x4 __attribute__((ext_vector_type(4)));

// ---- RNE f32 -> bf16 packing (static indexing only) ----
static __device__ __forceinline__ bf16x8 rne8(float4 a, float4 b) {
    float f[8] = {a.x, a.y, a.z, a.w, b.x, b.y, b.z, b.w};
    union { unsigned short us[8]; bf16x8 v; } U;
    #pragma unroll
    for (int i = 0; i < 8; ++i) {
        unsigned u = __float_as_uint(f[i]);
        U.us[i] = (unsigned short)((u + 0x7fffu + ((u >> 16) & 1u)) >> 16);
    }
    return U.v;
}

static __device__ __forceinline__ bf16x8 rne8s(float4 a, float4 b, float s) {
    float f[8] = {a.x, a.y, a.z, a.w, b.x, b.y, b.z, b.w};
    union { unsigned short us[8]; bf16x8 v; } U;
    #pragma unroll
    for (int i = 0; i < 8; ++i) {
        unsigned u = __float_as_uint(f[i] * s);
        U.us[i] = (unsigned short)((u + 0x7fffu + ((u >> 16) & 1u)) >> 16);
    }
    return U.v;
}

// ---------------- W -> bf16 B-fragment precompute (verified round 6) -------
// wf[(r*8 + j)*64 + lane], j = tt*2 + ks.
// Lane l (eh=l&15, kg=l>>4) holds W[r][16*tt + eh][32*ks + 8*kg + i], i=0..7.
__global__ void k_wfrag(const float* __restrict__ w, bf16x8* __restrict__ wf) {
    int r = blockIdx.x;
    int lane = threadIdx.x & 63;
    int eh = lane & 15, kg = lane >> 4;
    #pragma unroll
    for (int j = 0; j < 8; ++j) {
        int tt = j >> 1, ks = j & 1;
        const float4* p = reinterpret_cast<const float4*>(
            w + ((size_t)r << 12) + (size_t)(16 * tt + eh) * 64 + 32 * ks + 8 * kg);
        wf[(r * 8 + j) * 64 + lane] = rne8(p[0], p[1]);
    }
}

// meta generation S for chunk CC: per-lane edges (eh, eh+16) of the chunk
#define MLOAD(S, CC) { \
    int cc_ = (CC); if (cc_ > NCm1) cc_ = NCm1; \
    int b_ = cc_ * 32 + eh; \
    int ea_ = b_ > Em1 ? Em1 : b_; \
    int eb_ = (b_ + 16) > Em1 ? Em1 : (b_ + 16); \
    nd##S##0 = enode[ea_]; rt##S##0 = erating[ea_]; sc##S##0 = invc[ea_]; \
    nd##S##1 = enode[eb_]; rt##S##1 = erating[eb_]; sc##S##1 = invc[eb_]; }

// x set XS for the chunk whose meta is in MS
#define XLOADM(XS, MS) { \
    const float4* pa_ = reinterpret_cast<const float4*>(embed + ((size_t)nd##MS##0 << 6)); \
    const float4* pb_ = reinterpret_cast<const float4*>(embed + ((size_t)nd##MS##1 << 6)); \
    x##XS##00 = pa_[2 * kg]; x##XS##01 = pa_[2 * kg + 1]; \
    x##XS##02 = pa_[8 + 2 * kg]; x##XS##03 = pa_[9 + 2 * kg]; \
    x##XS##10 = pb_[2 * kg]; x##XS##11 = pb_[2 * kg + 1]; \
    x##XS##12 = pb_[8 + 2 * kg]; x##XS##13 = pb_[9 + 2 * kg]; }

// process chunk c (meta MP, x XC); prefetch x(c+GW) from MQ and meta(c+2GW) into MP
#define ITER(MP, MQ, XC, XN) { \
    XLOADM(XN, MQ) \
    int snd0 = nd##MP##0, snd1 = nd##MP##1; \
    int srt0 = rt##MP##0, srt1 = rt##MP##1; \
    float ssc0 = sc##MP##0, ssc1 = sc##MP##1; \
    bf16x8 a00 = rne8s(x##XC##00, x##XC##01, ssc0); \
    bf16x8 a01 = rne8s(x##XC##02, x##XC##03, ssc0); \
    bf16x8 a10 = rne8s(x##XC##10, x##XC##11, ssc1); \
    bf16x8 a11 = rne8s(x##XC##12, x##XC##13, ssc1); \
    MLOAD(MP, c + 2 * GW) \
    unsigned pres0 = 0, pres1 = 0; \
    _Pragma("unroll") \
    for (int rq = 0; rq < NUM_RATINGS; ++rq) { \
        if (__any(srt0 == rq)) pres0 |= 1u << rq; \
        if (__any(srt1 == rq)) pres1 |= 1u << rq; \
    } \
    f32x4 ac0[4], ac1[4]; \
    _Pragma("unroll") \
    for (int t_ = 0; t_ < 4; ++t_) { \
        ac0[t_] = (f32x4){0.f, 0.f, 0.f, 0.f}; \
        ac1[t_] = (f32x4){0.f, 0.f, 0.f, 0.f}; \
    } \
    _Pragma("unroll 1") \
    for (int r_ = 0; r_ < NUM_RATINGS; ++r_) { \
        if (!(((pres0 | pres1) >> r_) & 1u)) continue; \
        bf16x8 Bv[8]; \
        _Pragma("unroll") \
        for (int j_ = 0; j_ < 8; ++j_) Bv[j_] = swf[(r_ * 8 + j_) * 64 + lane]; \
        bf16x8 z_ = (bf16x8)(short)0; \
        if ((pres0 >> r_) & 1u) { \
            bf16x8 m0_ = (srt0 == r_) ? a00 : z_; \
            bf16x8 m1_ = (srt0 == r_) ? a01 : z_; \
            _Pragma("unroll") \
            for (int t_ = 0; t_ < 4; ++t_) { \
                ac0[t_] = __builtin_amdgcn_mfma_f32_16x16x32_bf16(m0_, Bv[2 * t_],     ac0[t_], 0, 0, 0); \
                ac0[t_] = __builtin_amdgcn_mfma_f32_16x16x32_bf16(m1_, Bv[2 * t_ + 1], ac0[t_], 0, 0, 0); \
            } \
        } \
        if ((pres1 >> r_) & 1u) { \
            bf16x8 m0_ = (srt1 == r_) ? a10 : z_; \
            bf16x8 m1_ = (srt1 == r_) ? a11 : z_; \
            _Pragma("unroll") \
            for (int t_ = 0; t_ < 4; ++t_) { \
                ac1[t_] = __builtin_amdgcn_mfma_f32_16x16x32_bf16(m0_, Bv[2 * t_],     ac1[t_], 0, 0, 0); \
                ac1[t_] = __builtin_amdgcn_mfma_f32_16x16x32_bf16(m1_, Bv[2 * t_ + 1], ac1[t_], 0, 0, 0); \
            } \
        } \
    } \
    int kg4 = kg << 2; \
    _Pragma("unroll") \
    for (int rg = 0; rg < 4; ++rg) { \
        int er0 = c * 32 + kg4 + rg; \
        int nda = __shfl(snd0, kg4 + rg, 64); \
        if (er0 < E) { \
            float* po = out + ((size_t)nda << 6) + eh; \
            __builtin_nontemporal_store(ac0[0][rg], po); \
            __builtin_nontemporal_store(ac0[1][rg], po + 16); \
            __builtin_nontemporal_store(ac0[2][rg], po + 32); \
            __builtin_nontemporal_store(ac0[3][rg], po + 48); \
        } \
        int er1 = c * 32 + 16 + kg4 + rg; \
        int ndb = __shfl(snd1, kg4 + rg, 64); \
        if (er1 < E) { \
            float* po = out + ((size_t)ndb << 6) + eh; \
            __builtin_nontemporal_store(ac1[0][rg], po); \
            __builtin_nontemporal_store(ac1[1][rg], po + 16); \
            __builtin_nontemporal_store(ac1[2][rg], po + 32); \
            __builtin_nontemporal_store(ac1[3][rg], po + 48); \
        } \
    } \
}

// ---------------- persistent main ----------------
// Natural edge order (coalesced IO), masked MFMA over present ratings,
// all-ratings B cached in one 80 KiB LDS copy, 2-deep cross-chunk pipeline.
// 1024-thread block, ONE block per CU (16 waves = 4 waves/EU).
// amdgpu_waves_per_eu(1,4): caps the backend's occupancy target at 4
// waves/EU so the register allocator budget is 128 VGPR — prevents the
// LDS-derived 8-waves/EU target that forced 64 VGPR + spills in r10/r11.
__global__ __launch_bounds__(1024)
__attribute__((amdgpu_waves_per_eu(1, 4)))
void k_main(
    const float* __restrict__ embed, const bf16x8* __restrict__ wf,
    const float* __restrict__ invc, const int* __restrict__ enode,
    const int* __restrict__ erating, float* __restrict__ out, int E) {

    __shared__ bf16x8 swf[NUM_RATINGS * 8 * 64];   // 80 KiB
    for (int i = threadIdx.x; i < NUM_RATINGS * 8 * 64; i += 1024)
        swf[i] = wf[i];
    __syncthreads();

    int lane = threadIdx.x & 63;
    int wv = threadIdx.x >> 6;          // 0..15
    int eh = lane & 15, kg = lane >> 4;

    int NC = (E + 31) >> 5;
    int NCm1 = NC - 1, Em1 = E - 1;
    int c = blockIdx.x * 16 + wv;
    if (c >= NC) return;

    int ndP0, ndP1, rtP0, rtP1; float scP0, scP1;
    int ndQ0, ndQ1, rtQ0, rtQ1; float scQ0, scQ1;
    float4 xX00, xX01, xX02, xX03, xX10, xX11, xX12, xX13;
    float4 xY00, xY01, xY02, xY03, xY10, xY11, xY12, xY13;

    MLOAD(P, c)
    MLOAD(Q, c + GW)
    XLOADM(X, P)

    while (1) {
        ITER(P, Q, X, Y)
        c += GW; if (c >= NC) break;
        ITER(Q, P, Y, X)
        c += GW; if (c >= NC) break;
    }
}

extern "C" void kernel_launch(void* const* d_in, const int* in_sizes, int n_in,
                              void* d_out, int out_size, void* d_ws, size_t ws_size,
                              hipStream_t stream) {
    const float* embed   = (const float*)d_in[0];
    const float* weights = (const float*)d_in[1];
    const float* invc    = (const float*)d_in[2];
    const int*   enode   = (const int*)d_in[3];
    const int*   erating = (const int*)d_in[4];
    float* out = (float*)d_out;

    int E = in_sizes[3];

    bf16x8* wf = (bf16x8*)d_ws;   // 80 KiB W fragments

    hipLaunchKernelGGL(k_wfrag, dim3(NUM_RATINGS), dim3(64), 0, stream, weights, wf);
    hipLaunchKernelGGL(k_main, dim3(GW / 16), dim3(1024), 0, stream,
                       embed, wf, invc, enode, erating, out, E);
}

// Round 13
// 139.304 us; speedup vs baseline: 1.2689x; 1.2640x over previous
//
#include <hip/hip_runtime.h>
#include <hip/hip_bf16.h>

#define NUM_RATINGS 10
#define RLDS 5    // ratings cached in LDS (40 KiB); rest read from global (L2)
#define GW 4096   // persistent waves = 1024 blocks x 4 waves (256 threads)

typedef short bf16x8 __attribute__((ext_vector_type(8)));
typedef float f32x4 __attribute__((ext_vector_type(4)));

// ---- RNE f32 -> bf16 packing (static indexing only) ----
static __device__ __forceinline__ bf16x8 rne8(float4 a, float4 b) {
    float f[8] = {a.x, a.y, a.z, a.w, b.x, b.y, b.z, b.w};
    union { unsigned short us[8]; bf16x8 v; } U;
    #pragma unroll
    for (int i = 0; i < 8; ++i) {
        unsigned u = __float_as_uint(f[i]);
        U.us[i] = (unsigned short)((u + 0x7fffu + ((u >> 16) & 1u)) >> 16);
    }
    return U.v;
}

static __device__ __forceinline__ bf16x8 rne8s(float4 a, float4 b, float s) {
    float f[8] = {a.x, a.y, a.z, a.w, b.x, b.y, b.z, b.w};
    union { unsigned short us[8]; bf16x8 v; } U;
    #pragma unroll
    for (int i = 0; i < 8; ++i) {
        unsigned u = __float_as_uint(f[i] * s);
        U.us[i] = (unsigned short)((u + 0x7fffu + ((u >> 16) & 1u)) >> 16);
    }
    return U.v;
}

// ---------------- W -> bf16 B-fragment precompute (verified round 6) -------
// wf[(r*8 + j)*64 + lane], j = tt*2 + ks.
// Lane l (eh=l&15, kg=l>>4) holds W[r][16*tt + eh][32*ks + 8*kg + i], i=0..7.
__global__ void k_wfrag(const float* __restrict__ w, bf16x8* __restrict__ wf) {
    int r = blockIdx.x;
    int lane = threadIdx.x & 63;
    int eh = lane & 15, kg = lane >> 4;
    #pragma unroll
    for (int j = 0; j < 8; ++j) {
        int tt = j >> 1, ks = j & 1;
        const float4* p = reinterpret_cast<const float4*>(
            w + ((size_t)r << 12) + (size_t)(16 * tt + eh) * 64 + 32 * ks + 8 * kg);
        wf[(r * 8 + j) * 64 + lane] = rne8(p[0], p[1]);
    }
}

// meta generation S for chunk CC: per-lane edges (eh, eh+16) of the chunk
#define MLOAD(S, CC) { \
    int cc_ = (CC); if (cc_ > NCm1) cc_ = NCm1; \
    int b_ = cc_ * 32 + eh; \
    int ea_ = b_ > Em1 ? Em1 : b_; \
    int eb_ = (b_ + 16) > Em1 ? Em1 : (b_ + 16); \
    nd##S##0 = enode[ea_]; rt##S##0 = erating[ea_]; sc##S##0 = invc[ea_]; \
    nd##S##1 = enode[eb_]; rt##S##1 = erating[eb_]; sc##S##1 = invc[eb_]; }

// x set XS for the chunk whose meta is in MS
#define XLOADM(XS, MS) { \
    const float4* pa_ = reinterpret_cast<const float4*>(embed + ((size_t)nd##MS##0 << 6)); \
    const float4* pb_ = reinterpret_cast<const float4*>(embed + ((size_t)nd##MS##1 << 6)); \
    x##XS##00 = pa_[2 * kg]; x##XS##01 = pa_[2 * kg + 1]; \
    x##XS##02 = pa_[8 + 2 * kg]; x##XS##03 = pa_[9 + 2 * kg]; \
    x##XS##10 = pb_[2 * kg]; x##XS##11 = pb_[2 * kg + 1]; \
    x##XS##12 = pb_[8 + 2 * kg]; x##XS##13 = pb_[9 + 2 * kg]; }

// process chunk c (meta MP, x XC); prefetch x(c+GW) from MQ and meta(c+2GW) into MP
#define ITER(MP, MQ, XC, XN) { \
    XLOADM(XN, MQ) \
    int snd0 = nd##MP##0, snd1 = nd##MP##1; \
    int srt0 = rt##MP##0, srt1 = rt##MP##1; \
    float ssc0 = sc##MP##0, ssc1 = sc##MP##1; \
    bf16x8 a00 = rne8s(x##XC##00, x##XC##01, ssc0); \
    bf16x8 a01 = rne8s(x##XC##02, x##XC##03, ssc0); \
    bf16x8 a10 = rne8s(x##XC##10, x##XC##11, ssc1); \
    bf16x8 a11 = rne8s(x##XC##12, x##XC##13, ssc1); \
    MLOAD(MP, c + 2 * GW) \
    unsigned pres0 = 0, pres1 = 0; \
    _Pragma("unroll") \
    for (int rq = 0; rq < NUM_RATINGS; ++rq) { \
        if (__any(srt0 == rq)) pres0 |= 1u << rq; \
        if (__any(srt1 == rq)) pres1 |= 1u << rq; \
    } \
    f32x4 ac0[4], ac1[4]; \
    _Pragma("unroll") \
    for (int t_ = 0; t_ < 4; ++t_) { \
        ac0[t_] = (f32x4){0.f, 0.f, 0.f, 0.f}; \
        ac1[t_] = (f32x4){0.f, 0.f, 0.f, 0.f}; \
    } \
    _Pragma("unroll 1") \
    for (int r_ = 0; r_ < NUM_RATINGS; ++r_) { \
        if (!(((pres0 | pres1) >> r_) & 1u)) continue; \
        bf16x8 Bv[8]; \
        if (r_ < RLDS) { \
            _Pragma("unroll") \
            for (int j_ = 0; j_ < 8; ++j_) Bv[j_] = swf[(r_ * 8 + j_) * 64 + lane]; \
        } else { \
            _Pragma("unroll") \
            for (int j_ = 0; j_ < 8; ++j_) Bv[j_] = wf[(r_ * 8 + j_) * 64 + lane]; \
        } \
        bf16x8 z_ = (bf16x8)(short)0; \
        if ((pres0 >> r_) & 1u) { \
            bf16x8 m0_ = (srt0 == r_) ? a00 : z_; \
            bf16x8 m1_ = (srt0 == r_) ? a01 : z_; \
            _Pragma("unroll") \
            for (int t_ = 0; t_ < 4; ++t_) { \
                ac0[t_] = __builtin_amdgcn_mfma_f32_16x16x32_bf16(m0_, Bv[2 * t_],     ac0[t_], 0, 0, 0); \
                ac0[t_] = __builtin_amdgcn_mfma_f32_16x16x32_bf16(m1_, Bv[2 * t_ + 1], ac0[t_], 0, 0, 0); \
            } \
        } \
        if ((pres1 >> r_) & 1u) { \
            bf16x8 m0_ = (srt1 == r_) ? a10 : z_; \
            bf16x8 m1_ = (srt1 == r_) ? a11 : z_; \
            _Pragma("unroll") \
            for (int t_ = 0; t_ < 4; ++t_) { \
                ac1[t_] = __builtin_amdgcn_mfma_f32_16x16x32_bf16(m0_, Bv[2 * t_],     ac1[t_], 0, 0, 0); \
                ac1[t_] = __builtin_amdgcn_mfma_f32_16x16x32_bf16(m1_, Bv[2 * t_ + 1], ac1[t_], 0, 0, 0); \
            } \
        } \
    } \
    int kg4 = kg << 2; \
    _Pragma("unroll") \
    for (int rg = 0; rg < 4; ++rg) { \
        int er0 = c * 32 + kg4 + rg; \
        int nda = __shfl(snd0, kg4 + rg, 64); \
        if (er0 < E) { \
            float* po = out + ((size_t)nda << 6) + eh; \
            __builtin_nontemporal_store(ac0[0][rg], po); \
            __builtin_nontemporal_store(ac0[1][rg], po + 16); \
            __builtin_nontemporal_store(ac0[2][rg], po + 32); \
            __builtin_nontemporal_store(ac0[3][rg], po + 48); \
        } \
        int er1 = c * 32 + 16 + kg4 + rg; \
        int ndb = __shfl(snd1, kg4 + rg, 64); \
        if (er1 < E) { \
            float* po = out + ((size_t)ndb << 6) + eh; \
            __builtin_nontemporal_store(ac1[0][rg], po); \
            __builtin_nontemporal_store(ac1[1][rg], po + 16); \
            __builtin_nontemporal_store(ac1[2][rg], po + 32); \
            __builtin_nontemporal_store(ac1[3][rg], po + 48); \
        } \
    } \
}

// ---------------- persistent main ----------------
// Round-9 verified body; LDS shrunk 80->40 KiB (ratings 0..4 in LDS, 5..9
// from global wf, which is 80 KiB and L2/L3-resident). 256-thread blocks:
// 4 blocks/CU by LDS => 16 waves/CU (2x round 9) with VGPR budget 128 —
// avoids the 64-VGPR spill cliff that killed r10-r12's big-block attempts.
// D layout (m89, verified r4-r9): row(edge) = 4*kg + rg, col(out) = 16*tt + eh.
__global__ __launch_bounds__(256) void k_main(
    const float* __restrict__ embed, const bf16x8* __restrict__ wf,
    const float* __restrict__ invc, const int* __restrict__ enode,
    const int* __restrict__ erating, float* __restrict__ out, int E) {

    __shared__ bf16x8 swf[RLDS * 8 * 64];   // 40 KiB
    for (int i = threadIdx.x; i < RLDS * 8 * 64; i += 256)
        swf[i] = wf[i];
    __syncthreads();

    int lane = threadIdx.x & 63;
    int wv = threadIdx.x >> 6;          // 0..3
    int eh = lane & 15, kg = lane >> 4;

    int NC = (E + 31) >> 5;
    int NCm1 = NC - 1, Em1 = E - 1;
    int c = blockIdx.x * 4 + wv;
    if (c >= NC) return;

    int ndP0, ndP1, rtP0, rtP1; float scP0, scP1;
    int ndQ0, ndQ1, rtQ0, rtQ1; float scQ0, scQ1;
    float4 xX00, xX01, xX02, xX03, xX10, xX11, xX12, xX13;
    float4 xY00, xY01, xY02, xY03, xY10, xY11, xY12, xY13;

    MLOAD(P, c)
    MLOAD(Q, c + GW)
    XLOADM(X, P)

    while (1) {
        ITER(P, Q, X, Y)
        c += GW; if (c >= NC) break;
        ITER(Q, P, Y, X)
        c += GW; if (c >= NC) break;
    }
}

extern "C" void kernel_launch(void* const* d_in, const int* in_sizes, int n_in,
                              void* d_out, int out_size, void* d_ws, size_t ws_size,
                              hipStream_t stream) {
    const float* embed   = (const float*)d_in[0];
    const float* weights = (const float*)d_in[1];
    const float* invc    = (const float*)d_in[2];
    const int*   enode   = (const int*)d_in[3];
    const int*   erating = (const int*)d_in[4];
    float* out = (float*)d_out;

    int E = in_sizes[3];

    bf16x8* wf = (bf16x8*)d_ws;   // 80 KiB W fragments

    hipLaunchKernelGGL(k_wfrag, dim3(NUM_RATINGS), dim3(64), 0, stream, weights, wf);
    hipLaunchKernelGGL(k_main, dim3(GW / 4), dim3(256), 0, stream,
                       embed, wf, invc, enode, erating, out, E);
}

// Round 14
// 124.680 us; speedup vs baseline: 1.4177x; 1.1173x over previous
//
#include <hip/hip_runtime.h>
#include <hip/hip_bf16.h>

#define NUM_RATINGS 10
#define WIN 1024
#define MAXT 74   // max padded tiles/window: 1024/16 + 10 pad-tails

typedef short bf16x8 __attribute__((ext_vector_type(8)));
typedef float f32x4 __attribute__((ext_vector_type(4)));

// ---- RNE f32 -> bf16 packing (static indexing only) ----
static __device__ __forceinline__ bf16x8 rne8(float4 a, float4 b) {
    float f[8] = {a.x, a.y, a.z, a.w, b.x, b.y, b.z, b.w};
    union { unsigned short us[8]; bf16x8 v; } U;
    #pragma unroll
    for (int i = 0; i < 8; ++i) {
        unsigned u = __float_as_uint(f[i]);
        U.us[i] = (unsigned short)((u + 0x7fffu + ((u >> 16) & 1u)) >> 16);
    }
    return U.v;
}

static __device__ __forceinline__ bf16x8 rne8s(float4 a, float4 b, float s) {
    float f[8] = {a.x, a.y, a.z, a.w, b.x, b.y, b.z, b.w};
    union { unsigned short us[8]; bf16x8 v; } U;
    #pragma unroll
    for (int i = 0; i < 8; ++i) {
        unsigned u = __float_as_uint(f[i] * s);
        U.us[i] = (unsigned short)((u + 0x7fffu + ((u >> 16) & 1u)) >> 16);
    }
    return U.v;
}

// ---------------- W -> bf16 B-fragment precompute (verified round 6) -------
// wf[(r*8 + j)*64 + lane], j = tt*2 + ks.
// Lane l (eh=l&15, kg=l>>4) holds W[r][16*tt + eh][32*ks + 8*kg + i], i=0..7.
__global__ void k_wfrag(const float* __restrict__ w, bf16x8* __restrict__ wf) {
    int r = blockIdx.x;
    int lane = threadIdx.x & 63;
    int eh = lane & 15, kg = lane >> 4;
    #pragma unroll
    for (int j = 0; j < 8; ++j) {
        int tt = j >> 1, ks = j & 1;
        const float4* p = reinterpret_cast<const float4*>(
            w + ((size_t)r << 12) + (size_t)(16 * tt + eh) * 64 + 32 * ks + 8 * kg);
        wf[(r * 8 + j) * 64 + lane] = rne8(p[0], p[1]);
    }
}

// ---------------- windowed local-sort main ----------------
// One block = one 1024-edge window. Phase 1: LDS counting sort by rating
// (padded buckets, pads marked nd=-1). Phase 2: 4 waves process contiguous
// ranges of rating-uniform 16-edge tiles; B from L2-hot global wf, reloaded
// only on rating change; 1-deep x prefetch across tiles. x-gathers and out
// stores are window-local (256 KB span) => DRAM-page-friendly.
// D layout (m89, verified r4-r13): row(edge) = 4*kg + rg, col(out) = 16*tt+eh.
__global__ __launch_bounds__(256) void k_main(
    const float* __restrict__ embed, const bf16x8* __restrict__ wf,
    const float* __restrict__ invc, const int* __restrict__ enode,
    const int* __restrict__ erating, float* __restrict__ out, int E) {

    __shared__ int2 smeta[MAXT * 16];          // 9472 B
    __shared__ int shist[NUM_RATINGS];
    __shared__ int spoff[NUM_RATINGS + 1];

    int tid = threadIdx.x;
    int base = blockIdx.x * WIN;

    if (tid < NUM_RATINGS) shist[tid] = 0;
    for (int i = tid; i < MAXT * 16; i += 256) smeta[i] = make_int2(-1, 0);
    __syncthreads();

    // histogram (4 edges/thread, coalesced); kk = unique index within bucket
    int er[4], rr[4], kk[4];
    #pragma unroll
    for (int i = 0; i < 4; ++i) {
        int e = base + i * 256 + tid;
        er[i] = e;
        if (e < E) {
            rr[i] = erating[e];
            kk[i] = atomicAdd(&shist[rr[i]], 1);
        }
    }
    __syncthreads();
    if (tid == 0) {
        int s = 0;
        #pragma unroll
        for (int r = 0; r < NUM_RATINGS; ++r) { spoff[r] = s; s += (shist[r] + 15) & ~15; }
        spoff[NUM_RATINGS] = s;
    }
    __syncthreads();
    // scatter into padded rating-sorted LDS slots
    #pragma unroll
    for (int i = 0; i < 4; ++i)
        if (er[i] < E)
            smeta[spoff[rr[i]] + kk[i]] =
                make_int2(enode[er[i]], __float_as_int(invc[er[i]]));
    __syncthreads();

    // uniform scalar copies
    int pf1 = spoff[1], pf2 = spoff[2], pf3 = spoff[3], pf4 = spoff[4];
    int pf5 = spoff[5], pf6 = spoff[6], pf7 = spoff[7], pf8 = spoff[8];
    int pf9 = spoff[9];
    int Tp = spoff[NUM_RATINGS] >> 4;

    int lane = tid & 63, wv = tid >> 6;
    int eh = lane & 15, kg = lane >> 4;

    int tpw = (Tp + 3) >> 2;
    int t0 = wv * tpw;
    int t1 = t0 + tpw; if (t1 > Tp) t1 = Tp;
    if (t0 >= t1) return;   // no barriers after this point

    // pipeline prologue: tile t0 meta + x
    int2 mc = smeta[(t0 << 4) + eh];
    {
        int ndc = mc.x < 0 ? 0 : mc.x;
        const float4* xp = reinterpret_cast<const float4*>(embed + ((size_t)ndc << 6));
        (void)xp;
    }
    const float4* xp0 = reinterpret_cast<const float4*>(
        embed + ((size_t)(mc.x < 0 ? 0 : mc.x) << 6));
    float4 xc0 = xp0[2 * kg], xc1 = xp0[2 * kg + 1];
    float4 xc2 = xp0[8 + 2 * kg], xc3 = xp0[9 + 2 * kg];

    int cur_r = -1;
    bf16x8 B[8];

    for (int t = t0; t < t1; ++t) {
        // prefetch next tile's meta + x (window-local gather)
        int tn = (t + 1 < t1) ? t + 1 : t;
        int2 mn = smeta[(tn << 4) + eh];
        const float4* xq = reinterpret_cast<const float4*>(
            embed + ((size_t)(mn.x < 0 ? 0 : mn.x) << 6));
        float4 xn0 = xq[2 * kg], xn1 = xq[2 * kg + 1];
        float4 xn2 = xq[8 + 2 * kg], xn3 = xq[9 + 2 * kg];

        // rating of tile t (uniform select chain; buckets are tile-aligned)
        int tslot = t << 4;
        int r = 0;
        r += tslot >= pf1; r += tslot >= pf2; r += tslot >= pf3;
        r += tslot >= pf4; r += tslot >= pf5; r += tslot >= pf6;
        r += tslot >= pf7; r += tslot >= pf8; r += tslot >= pf9;
        if (r != cur_r) {
            cur_r = r;
            #pragma unroll
            for (int j = 0; j < 8; ++j) B[j] = wf[(r * 8 + j) * 64 + lane];
        }

        float s_ = mc.x < 0 ? 0.f : __int_as_float(mc.y);
        bf16x8 a0 = rne8s(xc0, xc1, s_);
        bf16x8 a1 = rne8s(xc2, xc3, s_);

        f32x4 acc[4];
        #pragma unroll
        for (int tt = 0; tt < 4; ++tt) acc[tt] = (f32x4){0.f, 0.f, 0.f, 0.f};
        #pragma unroll
        for (int tt = 0; tt < 4; ++tt) {
            acc[tt] = __builtin_amdgcn_mfma_f32_16x16x32_bf16(a0, B[2 * tt],     acc[tt], 0, 0, 0);
            acc[tt] = __builtin_amdgcn_mfma_f32_16x16x32_bf16(a1, B[2 * tt + 1], acc[tt], 0, 0, 0);
        }

        // store: lane holds D[4kg+rg][16tt+eh]; node of edge 4kg+rg via shfl
        int vnd = mc.x;                 // -1 marks pad slot
        int kg4 = kg << 2;
        #pragma unroll
        for (int rg = 0; rg < 4; ++rg) {
            int nd2 = __shfl(vnd, kg4 + rg, 64);
            if (nd2 >= 0) {
                float* po = out + ((size_t)nd2 << 6) + eh;
                __builtin_nontemporal_store(acc[0][rg], po);
                __builtin_nontemporal_store(acc[1][rg], po + 16);
                __builtin_nontemporal_store(acc[2][rg], po + 32);
                __builtin_nontemporal_store(acc[3][rg], po + 48);
            }
        }

        mc = mn;
        xc0 = xn0; xc1 = xn1; xc2 = xn2; xc3 = xn3;
    }
}

extern "C" void kernel_launch(void* const* d_in, const int* in_sizes, int n_in,
                              void* d_out, int out_size, void* d_ws, size_t ws_size,
                              hipStream_t stream) {
    const float* embed   = (const float*)d_in[0];
    const float* weights = (const float*)d_in[1];
    const float* invc    = (const float*)d_in[2];
    const int*   enode   = (const int*)d_in[3];
    const int*   erating = (const int*)d_in[4];
    float* out = (float*)d_out;

    int E = in_sizes[3];

    bf16x8* wf = (bf16x8*)d_ws;   // 80 KiB W fragments (L2-hot)

    hipLaunchKernelGGL(k_wfrag, dim3(NUM_RATINGS), dim3(64), 0, stream, weights, wf);

    int nW = (E + WIN - 1) / WIN;
    hipLaunchKernelGGL(k_main, dim3(nW), dim3(256), 0, stream,
                       embed, wf, invc, enode, erating, out, E);
}